// Round 4
// baseline (520.254 us; speedup 1.0000x reference)
//
#include <hip/hip_runtime.h>
#include <hip/hip_fp16.h>
#include <math.h>

// B=8, H=8, S=4096, D=64. FACTOR=1 -> topk = S (full descending sort per column).
#define S 4096
#define D 64
#define NT 256
#define BH 64

__device__ __forceinline__ float2 cadd(float2 a, float2 b) { return make_float2(a.x + b.x, a.y + b.y); }
__device__ __forceinline__ float2 csub(float2 a, float2 b) { return make_float2(a.x - b.x, a.y - b.y); }
__device__ __forceinline__ float2 cmul(float2 a, float2 b) {
    return make_float2(a.x * b.x - a.y * b.y, a.x * b.y + a.y * b.x);
}

#define CE(a, b, desc) { float _mn = fminf(a, b), _mx = fmaxf(a, b); \
                         (a) = (desc) ? _mx : _mn; (b) = (desc) ? _mn : _mx; }

// In-register 16-point DFT (negative-exponent convention), natural in/out.
// Decomposition: j = j1 + 4*j2, s = s2 + 4*s1.
__device__ __forceinline__ void dft16(float2* e) {
    const float C1 = 0.9238795325112867f;   // cos(pi/8)
    const float S1 = 0.3826834323650898f;   // sin(pi/8)
    const float R2 = 0.7071067811865476f;
    const float2 W1 = make_float2(C1, -S1), W2 = make_float2(R2, -R2),
                 W3 = make_float2(S1, -C1), W6 = make_float2(-R2, -R2),
                 W9 = make_float2(-C1, S1);
    float2 b[16];
#pragma unroll
    for (int j1 = 0; j1 < 4; ++j1) {
        float2 a0 = e[j1], a1 = e[j1 + 4], a2 = e[j1 + 8], a3 = e[j1 + 12];
        float2 p = cadd(a0, a2), m = csub(a0, a2);
        float2 q = cadd(a1, a3), r = csub(a1, a3);
        float2 rm = make_float2(r.y, -r.x);     // -i*(a1-a3)
        b[4 * j1 + 0] = cadd(p, q);
        b[4 * j1 + 1] = cadd(m, rm);
        b[4 * j1 + 2] = csub(p, q);
        b[4 * j1 + 3] = csub(m, rm);
    }
#pragma unroll
    for (int s2 = 0; s2 < 4; ++s2) {
        float2 c0 = b[s2], c1 = b[4 + s2], c2 = b[8 + s2], c3 = b[12 + s2];
        if (s2 == 1) { c1 = cmul(c1, W1); c2 = cmul(c2, W2); c3 = cmul(c3, W3); }
        else if (s2 == 2) { c1 = cmul(c1, W2); c2 = make_float2(c2.y, -c2.x); c3 = cmul(c3, W6); }
        else if (s2 == 3) { c1 = cmul(c1, W3); c2 = cmul(c2, W6); c3 = cmul(c3, W9); }
        float2 p = cadd(c0, c2), m = csub(c0, c2);
        float2 q = cadd(c1, c3), r = csub(c1, c3);
        float2 rm = make_float2(r.y, -r.x);
        e[s2 + 0]  = cadd(p, q);
        e[s2 + 4]  = cadd(m, rm);
        e[s2 + 8]  = csub(p, q);
        e[s2 + 12] = csub(m, rm);
    }
}

// ---- kernel 1: coalesced read of q,k; write zt[bh][d][t] = half2(q,k) ----
__global__ __launch_bounds__(NT) void transpose_pack_kernel(
    const float* __restrict__ q, const float* __restrict__ kk,
    __half2* __restrict__ zt)
{
    __shared__ __half2 tile[64][65];
    const int tid = threadIdx.x;
    const int bh = blockIdx.x >> 6;
    const int t0 = (blockIdx.x & 63) << 6;
    const size_t ibase = ((size_t)bh * S + t0) * D;
#pragma unroll
    for (int m = 0; m < 16; ++m) {
        int idx = tid + NT * m;
        int t = idx >> 6, dd = idx & 63;
        float qa = q[ibase + (size_t)t * D + dd];
        float ka = kk[ibase + (size_t)t * D + dd];
        tile[t][dd] = __floats2half2_rn(qa, ka);
    }
    __syncthreads();
    const size_t obase = (size_t)bh * D * S + t0;
#pragma unroll
    for (int m = 0; m < 16; ++m) {
        int idx = tid + NT * m;
        int dd = idx >> 6, t = idx & 63;
        zt[obase + (size_t)dd * S + t] = tile[t][dd];
    }
}

// ---- kernel 2: per column: 3-pass radix-16 FFT corr -> sort -> softmax ----
// 4096 = 16^3. Thread m: pass1 DFT16 over j (x[m+256j]), twiddle w4096^{ms};
// pass2 (s,u): DFT16 over v (y_s[u+16v]), twiddle w256^{ub};
// pass3 (s,b): DFT16 over u -> X[256c+16b+s].
// Inverse = same forward structure applied to conj(C) (combine stores conj).
__global__ __launch_bounds__(NT, 4) void corr_sort_softmax_kernel(
    __half2* __restrict__ zt)
{
    __shared__ float2 L[S];        // exactly 32 KB; aliased by sort/reduce
    const int tid = threadIdx.x;
    const int col = blockIdx.x;
    float2 e[16];

    // ================= forward FFT of z = q + i*k =================
    const __half2* colp = zt + (size_t)col * S;
#pragma unroll
    for (int j = 0; j < 16; ++j)
        e[j] = __half22float2(colp[tid + 256 * j]);
    dft16(e);
    {   // twiddle w4096^{m*s} via recurrence on base = exp(-2*pi*i*m/4096)
        float sv, cv; sincospif((float)tid * (1.0f / 2048.0f), &sv, &cv);
        float2 base = make_float2(cv, -sv), t = base;
#pragma unroll
        for (int s = 1; s < 16; ++s) { e[s] = cmul(e[s], t); t = cmul(t, base); }
    }
#pragma unroll
    for (int s = 0; s < 16; ++s)
        L[256 * s + (tid ^ s)] = e[s];        // row s, pos m, xor-s swizzle
    __syncthreads();
    {
        const int s = tid >> 4, u = tid & 15;
#pragma unroll
        for (int v = 0; v < 16; ++v)
            e[v] = L[256 * s + ((u + 16 * v) ^ s)];
        dft16(e);                              // over v -> b
        float sv, cv; sincospif((float)u * (1.0f / 128.0f), &sv, &cv);
        float2 base = make_float2(cv, -sv), t = base;
#pragma unroll
        for (int b = 1; b < 16; ++b) { e[b] = cmul(e[b], t); t = cmul(t, base); }
        __syncthreads();                       // row readers done
#pragma unroll
        for (int b = 0; b < 16; ++b)
            L[256 * s + 16 * u + ((b + u) & 15)] = e[b];   // rotate swizzle
        __syncthreads();
#pragma unroll
        for (int u2 = 0; u2 < 16; ++u2)
            e[u2] = L[256 * s + 16 * u2 + ((u + u2) & 15)]; // b2 == u bits
        dft16(e);                              // over u -> c; X[256c+16b+s]
        __syncthreads();                       // readers done before X scatter
#pragma unroll
        for (int c = 0; c < 16; ++c) {
            int k = 256 * c + 16 * u + s;      // u here == b2 (same low bits)
            L[k ^ ((k >> 4) & 15)] = e[c];
        }
    }
    __syncthreads();

    // ================= spectral combine (natural domain) =================
    // Q,K unpack at (f, S-f); C = Q*conj(K); store conj(C) everywhere so a
    // forward transform of the stored data yields S * corr (real part).
#pragma unroll
    for (int m = 0; m < 8; ++m) {
        int f = tid + 256 * m;
        if (f == 0) {
            float2 Z0 = L[0];                  // phys(0)=0
            L[0] = make_float2(Z0.x * Z0.y, 0.0f);
            float2 Zh = L[2048];               // phys(2048)=2048
            L[2048] = make_float2(Zh.x * Zh.y, 0.0f);
        } else {
            int g = S - f;
            int pf = f ^ ((f >> 4) & 15);
            int pg = g ^ ((g >> 4) & 15);
            float2 Zf = L[pf], Zn = L[pg];
            float2 Q = make_float2(0.5f * (Zf.x + Zn.x), 0.5f * (Zf.y - Zn.y));
            float2 K = make_float2(0.5f * (Zf.y + Zn.y), -0.5f * (Zf.x - Zn.x));
            float2 C = make_float2(Q.x * K.x + Q.y * K.y, Q.y * K.x - Q.x * K.y);
            L[pf] = make_float2(C.x, -C.y);
            L[pg] = C;
        }
    }
    __syncthreads();

    // ================= inverse FFT (forward on stored conj data) =========
#pragma unroll
    for (int j = 0; j < 16; ++j) {
        int k = tid + 256 * j;
        e[j] = L[k ^ ((k >> 4) & 15)];
    }
    __syncthreads();                           // scattered reads done
    dft16(e);
    {
        float sv, cv; sincospif((float)tid * (1.0f / 2048.0f), &sv, &cv);
        float2 base = make_float2(cv, -sv), t = base;
#pragma unroll
        for (int s = 1; s < 16; ++s) { e[s] = cmul(e[s], t); t = cmul(t, base); }
    }
#pragma unroll
    for (int s = 0; s < 16; ++s)
        L[256 * s + (tid ^ s)] = e[s];
    __syncthreads();
    {
        const int s = tid >> 4, u = tid & 15;
#pragma unroll
        for (int v = 0; v < 16; ++v)
            e[v] = L[256 * s + ((u + 16 * v) ^ s)];
        dft16(e);
        float sv, cv; sincospif((float)u * (1.0f / 128.0f), &sv, &cv);
        float2 base = make_float2(cv, -sv), t = base;
#pragma unroll
        for (int b = 1; b < 16; ++b) { e[b] = cmul(e[b], t); t = cmul(t, base); }
        __syncthreads();
#pragma unroll
        for (int b = 0; b < 16; ++b)
            L[256 * s + 16 * u + ((b + u) & 15)] = e[b];
        __syncthreads();
#pragma unroll
        for (int u2 = 0; u2 < 16; ++u2)
            e[u2] = L[256 * s + 16 * u2 + ((u + u2) & 15)];
        dft16(e);   // final: e[c].x = S * corr at some index (order irrelevant)
    }

    // corr values straight into the sort's register set (bitonic networks are
    // data-oblivious: any initial data->virtual-position mapping sorts fine).
    float w[16];
#pragma unroll
    for (int c = 0; c < 16; ++c)
        w[c] = e[c].x * (1.0f / (float)S);

    // ---- bitonic sort, descending; thread t owns virtual slots 16t..16t+15
#pragma unroll
    for (int m = 0; m < 16; m += 2) CE(w[m], w[m + 1], ((m & 2) == 0));
#pragma unroll
    for (int j = 2; j >= 1; j >>= 1)
#pragma unroll
        for (int m = 0; m < 16; ++m)
            if ((m & j) == 0) CE(w[m], w[m | j], ((m & 4) == 0));
#pragma unroll
    for (int j = 4; j >= 1; j >>= 1)
#pragma unroll
        for (int m = 0; m < 16; ++m)
            if ((m & j) == 0) CE(w[m], w[m | j], ((m & 8) == 0));
    {
        const bool d16 = ((tid & 1) == 0);
#pragma unroll
        for (int j = 8; j >= 1; j >>= 1)
#pragma unroll
            for (int m = 0; m < 16; ++m)
                if ((m & j) == 0) CE(w[m], w[m | j], d16);
    }
    {
        float* s17 = (float*)L;
        for (int k2 = 32; k2 <= S; k2 <<= 1) {
            const bool desc = (((tid << 4) & k2) == 0);
            for (int j = k2 >> 1; j >= 16; j >>= 1) {
                const int mask = j >> 4;
                const bool side = (tid & mask) != 0;
                const bool wantmax = (desc != side);
                if (mask < 64) {
#pragma unroll
                    for (int m = 0; m < 16; ++m) {
                        float pv = __shfl_xor(w[m], mask, 64);
                        w[m] = wantmax ? fmaxf(w[m], pv) : fminf(w[m], pv);
                    }
                } else {
                    __syncthreads();
#pragma unroll
                    for (int m = 0; m < 16; ++m) s17[17 * tid + m] = w[m];
                    __syncthreads();
                    const int pt = tid ^ mask;
#pragma unroll
                    for (int m = 0; m < 16; ++m) {
                        float pv = s17[17 * pt + m];
                        w[m] = wantmax ? fmaxf(w[m], pv) : fminf(w[m], pv);
                    }
                }
            }
#pragma unroll
            for (int j = 8; j >= 1; j >>= 1)
#pragma unroll
                for (int m = 0; m < 16; ++m)
                    if ((m & j) == 0) CE(w[m], w[m | j], desc);
        }
    }

    // softmax over sorted axis; global max = thread 0's w[0]
    __syncthreads();
    float* red = (float*)L;
    if (tid == 0) red[0] = w[0];
    __syncthreads();
    const float mx = red[0];
    float part = 0.0f;
#pragma unroll
    for (int m = 0; m < 16; ++m) { w[m] = __expf(w[m] - mx); part += w[m]; }
#pragma unroll
    for (int off = 32; off > 0; off >>= 1) part += __shfl_down(part, off);
    if ((tid & 63) == 0) red[4 + (tid >> 6)] = part;
    __syncthreads();
    const float inv = 1.0f / (red[4] + red[5] + red[6] + red[7]);

    // weights overwrite THIS block's own zt column: float layout [col][i]
    float4* wout = (float4*)((float*)(zt + (size_t)col * S) + 16 * tid);
#pragma unroll
    for (int g = 0; g < 4; ++g)
        wout[g] = make_float4(w[4 * g] * inv, w[4 * g + 1] * inv,
                              w[4 * g + 2] * inv, w[4 * g + 3] * inv);
}

// ---- kernel 3: out[bh][i][l] = sum_j wt[bh][j][i] * v[bh][j][l] ----
__global__ __launch_bounds__(NT) void mix_kernel(
    const float* __restrict__ wt, const float* __restrict__ v,
    float* __restrict__ out)
{
    __shared__ float V[D][D];
    __shared__ float W[D][D + 4];
    const int tid = threadIdx.x;
    const int bh = blockIdx.x >> 6;
    const int tile = blockIdx.x & 63;

    const float* wsrc = wt + (size_t)bh * D * S + (size_t)tile * D;
    const float* vsrc = v + (size_t)bh * S * D;
    for (int idx = tid; idx < D * D; idx += NT) {
        int j = idx >> 6, l = idx & 63;
        V[j][l] = vsrc[j * D + l];
        W[j][l] = wsrc[(size_t)j * S + l];
    }
    __syncthreads();

    const int tx = tid & 15;
    const int ty = tid >> 4;
    float acc[4][4];
#pragma unroll
    for (int r = 0; r < 4; ++r)
#pragma unroll
        for (int c = 0; c < 4; ++c) acc[r][c] = 0.0f;

    for (int j = 0; j < D; ++j) {
        float4 vv = *(const float4*)&V[j][tx * 4];
        float4 ww = *(const float4*)&W[j][ty * 4];
        const float wr[4] = {ww.x, ww.y, ww.z, ww.w};
        const float vc[4] = {vv.x, vv.y, vv.z, vv.w};
#pragma unroll
        for (int r = 0; r < 4; ++r)
#pragma unroll
            for (int c = 0; c < 4; ++c) acc[r][c] += wr[r] * vc[c];
    }
    float* obase = out + ((size_t)bh * S + (size_t)tile * D + ty * 4) * D + tx * 4;
#pragma unroll
    for (int r = 0; r < 4; ++r)
        *(float4*)(obase + r * D) = make_float4(acc[r][0], acc[r][1], acc[r][2], acc[r][3]);
}

extern "C" void kernel_launch(void* const* d_in, const int* in_sizes, int n_in,
                              void* d_out, int out_size, void* d_ws, size_t ws_size,
                              hipStream_t stream) {
    const float* q = (const float*)d_in[0];
    const float* k = (const float*)d_in[1];
    const float* v = (const float*)d_in[2];
    float* out = (float*)d_out;
    __half2* zt = (__half2*)d_ws;          // 64 MB: [bh][d][t] half2(q,k)
    const float* wt = (const float*)d_ws;  // corr overwrites columns with weights

    transpose_pack_kernel<<<dim3(BH * 64), dim3(NT), 0, stream>>>(q, k, zt);
    corr_sort_softmax_kernel<<<dim3(BH * D), dim3(NT), 0, stream>>>(zt);
    mix_kernel<<<dim3(BH * (S / D)), dim3(NT), 0, stream>>>(wt, v, out);
}

// Round 5
// 481.831 us; speedup vs baseline: 1.0797x; 1.0797x over previous
//
#include <hip/hip_runtime.h>
#include <hip/hip_fp16.h>
#include <math.h>

// B=8, H=8, S=4096, D=64. FACTOR=1 -> topk = S (full descending sort per column).
#define S 4096
#define D 64
#define NT 256
#define BH 64

__device__ __forceinline__ float2 cadd(float2 a, float2 b) { return make_float2(a.x + b.x, a.y + b.y); }
__device__ __forceinline__ float2 csub(float2 a, float2 b) { return make_float2(a.x - b.x, a.y - b.y); }
__device__ __forceinline__ float2 cmul(float2 a, float2 b) {
    return make_float2(a.x * b.x - a.y * b.y, a.x * b.y + a.y * b.x);
}

#define CE(a, b, desc) { float _mn = fminf(a, b), _mx = fmaxf(a, b); \
                         (a) = (desc) ? _mx : _mn; (b) = (desc) ? _mn : _mx; }

// In-register 16-point DFT (negative-exponent convention), natural in/out.
// Decomposition: j = j1 + 4*j2, s = s2 + 4*s1.
__device__ __forceinline__ void dft16(float2* e) {
    const float C1 = 0.9238795325112867f;   // cos(pi/8)
    const float S1 = 0.3826834323650898f;   // sin(pi/8)
    const float R2 = 0.7071067811865476f;
    const float2 W1 = make_float2(C1, -S1), W2 = make_float2(R2, -R2),
                 W3 = make_float2(S1, -C1), W6 = make_float2(-R2, -R2),
                 W9 = make_float2(-C1, S1);
    float2 b[16];
#pragma unroll
    for (int j1 = 0; j1 < 4; ++j1) {
        float2 a0 = e[j1], a1 = e[j1 + 4], a2 = e[j1 + 8], a3 = e[j1 + 12];
        float2 p = cadd(a0, a2), m = csub(a0, a2);
        float2 q = cadd(a1, a3), r = csub(a1, a3);
        float2 rm = make_float2(r.y, -r.x);     // -i*(a1-a3)
        b[4 * j1 + 0] = cadd(p, q);
        b[4 * j1 + 1] = cadd(m, rm);
        b[4 * j1 + 2] = csub(p, q);
        b[4 * j1 + 3] = csub(m, rm);
    }
#pragma unroll
    for (int s2 = 0; s2 < 4; ++s2) {
        float2 c0 = b[s2], c1 = b[4 + s2], c2 = b[8 + s2], c3 = b[12 + s2];
        if (s2 == 1) { c1 = cmul(c1, W1); c2 = cmul(c2, W2); c3 = cmul(c3, W3); }
        else if (s2 == 2) { c1 = cmul(c1, W2); c2 = make_float2(c2.y, -c2.x); c3 = cmul(c3, W6); }
        else if (s2 == 3) { c1 = cmul(c1, W3); c2 = cmul(c2, W6); c3 = cmul(c3, W9); }
        float2 p = cadd(c0, c2), m = csub(c0, c2);
        float2 q = cadd(c1, c3), r = csub(c1, c3);
        float2 rm = make_float2(r.y, -r.x);
        e[s2 + 0]  = cadd(p, q);
        e[s2 + 4]  = cadd(m, rm);
        e[s2 + 8]  = csub(p, q);
        e[s2 + 12] = csub(m, rm);
    }
}

// ---- kernel 1: coalesced read of q,k; write zt[bh][d][t] = half2(q,k) ----
__global__ __launch_bounds__(NT) void transpose_pack_kernel(
    const float* __restrict__ q, const float* __restrict__ kk,
    __half2* __restrict__ zt)
{
    __shared__ __half2 tile[64][65];
    const int tid = threadIdx.x;
    const int bh = blockIdx.x >> 6;
    const int t0 = (blockIdx.x & 63) << 6;
    const size_t ibase = ((size_t)bh * S + t0) * D;
#pragma unroll
    for (int m = 0; m < 16; ++m) {
        int idx = tid + NT * m;
        int t = idx >> 6, dd = idx & 63;
        float qa = q[ibase + (size_t)t * D + dd];
        float ka = kk[ibase + (size_t)t * D + dd];
        tile[t][dd] = __floats2half2_rn(qa, ka);
    }
    __syncthreads();
    const size_t obase = (size_t)bh * D * S + t0;
#pragma unroll
    for (int m = 0; m < 16; ++m) {
        int idx = tid + NT * m;
        int dd = idx >> 6, t = idx & 63;
        zt[obase + (size_t)dd * S + t] = tile[t][dd];
    }
}

// ---- kernel 2: per column: 3-pass radix-16 FFT corr -> sort -> softmax ----
// 4096 = 16^3. Thread m: pass1 DFT16 over j (x[m+256j]), twiddle w4096^{ms};
// pass2 (s,u): DFT16 over v (y_s[u+16v]), twiddle w256^{ub};
// pass3 (s,b): DFT16 over u -> X[256c+16b+s].
// Inverse = same forward structure applied to conj(C) (combine stores conj).
// launch_bounds (NT,2): 256-VGPR budget — the (NT,4) variant capped at 64
// VGPRs and spilled ~700 MB/dispatch to scratch (R4 counters).
__global__ __launch_bounds__(NT, 2) void corr_sort_softmax_kernel(
    __half2* __restrict__ zt)
{
    __shared__ float2 L[S];        // exactly 32 KB; aliased by sort/reduce
    const int tid = threadIdx.x;
    const int col = blockIdx.x;
    float2 e[16];

    // ================= forward FFT of z = q + i*k =================
    const __half2* colp = zt + (size_t)col * S;
#pragma unroll
    for (int j = 0; j < 16; ++j)
        e[j] = __half22float2(colp[tid + 256 * j]);
    dft16(e);
    {   // twiddle w4096^{m*s} via recurrence on base = exp(-2*pi*i*m/4096)
        float sv, cv; sincospif((float)tid * (1.0f / 2048.0f), &sv, &cv);
        float2 base = make_float2(cv, -sv), t = base;
#pragma unroll
        for (int s = 1; s < 16; ++s) { e[s] = cmul(e[s], t); t = cmul(t, base); }
    }
#pragma unroll
    for (int s = 0; s < 16; ++s)
        L[256 * s + (tid ^ s)] = e[s];        // row s, pos m, xor-s swizzle
    __syncthreads();
    {
        const int s = tid >> 4, u = tid & 15;
#pragma unroll
        for (int v = 0; v < 16; ++v)
            e[v] = L[256 * s + ((u + 16 * v) ^ s)];
        dft16(e);                              // over v -> b
        float sv, cv; sincospif((float)u * (1.0f / 128.0f), &sv, &cv);
        float2 base = make_float2(cv, -sv), t = base;
#pragma unroll
        for (int b = 1; b < 16; ++b) { e[b] = cmul(e[b], t); t = cmul(t, base); }
        __syncthreads();                       // row readers done
#pragma unroll
        for (int b = 0; b < 16; ++b)
            L[256 * s + 16 * u + ((b + u) & 15)] = e[b];   // rotate swizzle
        __syncthreads();
#pragma unroll
        for (int u2 = 0; u2 < 16; ++u2)
            e[u2] = L[256 * s + 16 * u2 + ((u + u2) & 15)]; // b2 == u bits
        dft16(e);                              // over u -> c; X[256c+16b+s]
        __syncthreads();                       // readers done before X scatter
#pragma unroll
        for (int c = 0; c < 16; ++c) {
            int k = 256 * c + 16 * u + s;      // u here == b2 (same low bits)
            L[k ^ ((k >> 4) & 15)] = e[c];
        }
    }
    __syncthreads();

    // ================= spectral combine (natural domain) =================
    // Q,K unpack at (f, S-f); C = Q*conj(K); store conj(C) everywhere so a
    // forward transform of the stored data yields S * corr (real part).
#pragma unroll
    for (int m = 0; m < 8; ++m) {
        int f = tid + 256 * m;
        if (f == 0) {
            float2 Z0 = L[0];                  // phys(0)=0
            L[0] = make_float2(Z0.x * Z0.y, 0.0f);
            float2 Zh = L[2048];               // phys(2048)=2048
            L[2048] = make_float2(Zh.x * Zh.y, 0.0f);
        } else {
            int g = S - f;
            int pf = f ^ ((f >> 4) & 15);
            int pg = g ^ ((g >> 4) & 15);
            float2 Zf = L[pf], Zn = L[pg];
            float2 Q = make_float2(0.5f * (Zf.x + Zn.x), 0.5f * (Zf.y - Zn.y));
            float2 K = make_float2(0.5f * (Zf.y + Zn.y), -0.5f * (Zf.x - Zn.x));
            float2 C = make_float2(Q.x * K.x + Q.y * K.y, Q.y * K.x - Q.x * K.y);
            L[pf] = make_float2(C.x, -C.y);
            L[pg] = C;
        }
    }
    __syncthreads();

    // ================= inverse FFT (forward on stored conj data) =========
#pragma unroll
    for (int j = 0; j < 16; ++j) {
        int k = tid + 256 * j;
        e[j] = L[k ^ ((k >> 4) & 15)];
    }
    __syncthreads();                           // scattered reads done
    dft16(e);
    {
        float sv, cv; sincospif((float)tid * (1.0f / 2048.0f), &sv, &cv);
        float2 base = make_float2(cv, -sv), t = base;
#pragma unroll
        for (int s = 1; s < 16; ++s) { e[s] = cmul(e[s], t); t = cmul(t, base); }
    }
#pragma unroll
    for (int s = 0; s < 16; ++s)
        L[256 * s + (tid ^ s)] = e[s];
    __syncthreads();
    {
        const int s = tid >> 4, u = tid & 15;
#pragma unroll
        for (int v = 0; v < 16; ++v)
            e[v] = L[256 * s + ((u + 16 * v) ^ s)];
        dft16(e);
        float sv, cv; sincospif((float)u * (1.0f / 128.0f), &sv, &cv);
        float2 base = make_float2(cv, -sv), t = base;
#pragma unroll
        for (int b = 1; b < 16; ++b) { e[b] = cmul(e[b], t); t = cmul(t, base); }
        __syncthreads();
#pragma unroll
        for (int b = 0; b < 16; ++b)
            L[256 * s + 16 * u + ((b + u) & 15)] = e[b];
        __syncthreads();
#pragma unroll
        for (int u2 = 0; u2 < 16; ++u2)
            e[u2] = L[256 * s + 16 * u2 + ((u + u2) & 15)];
        dft16(e);   // final: e[c].x = S * corr at some index (order irrelevant)
    }

    // corr values straight into the sort's register set (bitonic networks are
    // data-oblivious: any initial data->virtual-position mapping sorts fine).
    float w[16];
#pragma unroll
    for (int c = 0; c < 16; ++c)
        w[c] = e[c].x * (1.0f / (float)S);

    // ---- bitonic sort, descending; thread t owns virtual slots 16t..16t+15
#pragma unroll
    for (int m = 0; m < 16; m += 2) CE(w[m], w[m + 1], ((m & 2) == 0));
#pragma unroll
    for (int j = 2; j >= 1; j >>= 1)
#pragma unroll
        for (int m = 0; m < 16; ++m)
            if ((m & j) == 0) CE(w[m], w[m | j], ((m & 4) == 0));
#pragma unroll
    for (int j = 4; j >= 1; j >>= 1)
#pragma unroll
        for (int m = 0; m < 16; ++m)
            if ((m & j) == 0) CE(w[m], w[m | j], ((m & 8) == 0));
    {
        const bool d16 = ((tid & 1) == 0);
#pragma unroll
        for (int j = 8; j >= 1; j >>= 1)
#pragma unroll
            for (int m = 0; m < 16; ++m)
                if ((m & j) == 0) CE(w[m], w[m | j], d16);
    }
    {
        float* s17 = (float*)L;
        for (int k2 = 32; k2 <= S; k2 <<= 1) {
            const bool desc = (((tid << 4) & k2) == 0);
            for (int j = k2 >> 1; j >= 16; j >>= 1) {
                const int mask = j >> 4;
                const bool side = (tid & mask) != 0;
                const bool wantmax = (desc != side);
                if (mask < 64) {
#pragma unroll
                    for (int m = 0; m < 16; ++m) {
                        float pv = __shfl_xor(w[m], mask, 64);
                        w[m] = wantmax ? fmaxf(w[m], pv) : fminf(w[m], pv);
                    }
                } else {
                    __syncthreads();
#pragma unroll
                    for (int m = 0; m < 16; ++m) s17[17 * tid + m] = w[m];
                    __syncthreads();
                    const int pt = tid ^ mask;
#pragma unroll
                    for (int m = 0; m < 16; ++m) {
                        float pv = s17[17 * pt + m];
                        w[m] = wantmax ? fmaxf(w[m], pv) : fminf(w[m], pv);
                    }
                }
            }
#pragma unroll
            for (int j = 8; j >= 1; j >>= 1)
#pragma unroll
                for (int m = 0; m < 16; ++m)
                    if ((m & j) == 0) CE(w[m], w[m | j], desc);
        }
    }

    // softmax over sorted axis; global max = thread 0's w[0]
    __syncthreads();
    float* red = (float*)L;
    if (tid == 0) red[0] = w[0];
    __syncthreads();
    const float mx = red[0];
    float part = 0.0f;
#pragma unroll
    for (int m = 0; m < 16; ++m) { w[m] = __expf(w[m] - mx); part += w[m]; }
#pragma unroll
    for (int off = 32; off > 0; off >>= 1) part += __shfl_down(part, off);
    if ((tid & 63) == 0) red[4 + (tid >> 6)] = part;
    __syncthreads();
    const float inv = 1.0f / (red[4] + red[5] + red[6] + red[7]);

    // weights overwrite THIS block's own zt column: float layout [col][i]
    float4* wout = (float4*)((float*)(zt + (size_t)col * S) + 16 * tid);
#pragma unroll
    for (int g = 0; g < 4; ++g)
        wout[g] = make_float4(w[4 * g] * inv, w[4 * g + 1] * inv,
                              w[4 * g + 2] * inv, w[4 * g + 3] * inv);
}

// ---- kernel 3: out[bh][i][l] = sum_j wt[bh][j][i] * v[bh][j][l] ----
__global__ __launch_bounds__(NT) void mix_kernel(
    const float* __restrict__ wt, const float* __restrict__ v,
    float* __restrict__ out)
{
    __shared__ float V[D][D];
    __shared__ float W[D][D + 4];
    const int tid = threadIdx.x;
    const int bh = blockIdx.x >> 6;
    const int tile = blockIdx.x & 63;

    const float* wsrc = wt + (size_t)bh * D * S + (size_t)tile * D;
    const float* vsrc = v + (size_t)bh * S * D;
    for (int idx = tid; idx < D * D; idx += NT) {
        int j = idx >> 6, l = idx & 63;
        V[j][l] = vsrc[j * D + l];
        W[j][l] = wsrc[(size_t)j * S + l];
    }
    __syncthreads();

    const int tx = tid & 15;
    const int ty = tid >> 4;
    float acc[4][4];
#pragma unroll
    for (int r = 0; r < 4; ++r)
#pragma unroll
        for (int c = 0; c < 4; ++c) acc[r][c] = 0.0f;

    for (int j = 0; j < D; ++j) {
        float4 vv = *(const float4*)&V[j][tx * 4];
        float4 ww = *(const float4*)&W[j][ty * 4];
        const float wr[4] = {ww.x, ww.y, ww.z, ww.w};
        const float vc[4] = {vv.x, vv.y, vv.z, vv.w};
#pragma unroll
        for (int r = 0; r < 4; ++r)
#pragma unroll
            for (int c = 0; c < 4; ++c) acc[r][c] += wr[r] * vc[c];
    }
    float* obase = out + ((size_t)bh * S + (size_t)tile * D + ty * 4) * D + tx * 4;
#pragma unroll
    for (int r = 0; r < 4; ++r)
        *(float4*)(obase + r * D) = make_float4(acc[r][0], acc[r][1], acc[r][2], acc[r][3]);
}

extern "C" void kernel_launch(void* const* d_in, const int* in_sizes, int n_in,
                              void* d_out, int out_size, void* d_ws, size_t ws_size,
                              hipStream_t stream) {
    const float* q = (const float*)d_in[0];
    const float* k = (const float*)d_in[1];
    const float* v = (const float*)d_in[2];
    float* out = (float*)d_out;
    __half2* zt = (__half2*)d_ws;          // 64 MB: [bh][d][t] half2(q,k)
    const float* wt = (const float*)d_ws;  // corr overwrites columns with weights

    transpose_pack_kernel<<<dim3(BH * 64), dim3(NT), 0, stream>>>(q, k, zt);
    corr_sort_softmax_kernel<<<dim3(BH * D), dim3(NT), 0, stream>>>(zt);
    mix_kernel<<<dim3(BH * (S / D)), dim3(NT), 0, stream>>>(wt, v, out);
}